// Round 2
// baseline (364.535 us; speedup 1.0000x reference)
//
#include <hip/hip_runtime.h>
#include <float.h>
#include <math.h>

#define NUM_USERS 100000
#define NUM_ITEMS 50000
#define NNODES    150000
#define DIM       64
#define NEDGE     2000000
#define BATCH     1024
#define SEL_CAP   (1 << 18)
#define LOGIT_BLOCKS 512

#define SLICES   512                    // edge slices
#define EPS      3908                   // ceil(NEDGE/SLICES) rounded to x4
#define NBUK     293                    // buckets of 512 nodes (293*512=150016)

__device__ __forceinline__ float wave_sum64(float v) {
    #pragma unroll
    for (int off = 32; off > 0; off >>= 1) v += __shfl_xor(v, off, 64);
    return v;
}

__device__ __forceinline__ float bf2f(unsigned short s) {
    return __uint_as_float(((unsigned int)s) << 16);
}
__device__ __forceinline__ unsigned short f2bf(float f) {   // RNE
    unsigned int u = __float_as_uint(f);
    return (unsigned short)((u + 0x7fffu + ((u >> 16) & 1u)) >> 16);
}

// ---- stage 1: per-slice 293-bucket col histograms + u8 ranks + deg atomics
//      + fused batch-selection. Row side needs only deg[] -> global atomics.

__global__ __launch_bounds__(512) void bhist_kernel(
        const int* __restrict__ row, const int* __restrict__ col,
        const int* __restrict__ ucnt, int* __restrict__ deg,
        unsigned short* __restrict__ cntC, unsigned char* __restrict__ rkC,
        int* __restrict__ n_sel, int* __restrict__ sel_col, float* __restrict__ sel_w) {
    __shared__ unsigned int hc[NBUK];
    __shared__ int lcnt, lbase;
    __shared__ int2 buf[256];
    int blk = blockIdx.x, t = threadIdx.x;
    for (int i = t; i < NBUK; i += 512) hc[i] = 0;
    if (t == 0) lcnt = 0;
    __syncthreads();
    int e0 = blk * EPS;
    int e1 = e0 + EPS; if (e1 > NEDGE) e1 = NEDGE;
    for (int base = e0 + t * 4; base < e1; base += 2048) {
        if (base + 4 <= e1) {
            int4 r4 = *(const int4*)(row + base);
            int4 c4 = *(const int4*)(col + base);
            uchar4 b4;
            b4.x = (unsigned char)atomicAdd(&hc[c4.x >> 9], 1u);
            b4.y = (unsigned char)atomicAdd(&hc[c4.y >> 9], 1u);
            b4.z = (unsigned char)atomicAdd(&hc[c4.z >> 9], 1u);
            b4.w = (unsigned char)atomicAdd(&hc[c4.w >> 9], 1u);
            *(uchar4*)(rkC + base) = b4;
            atomicAdd(&deg[r4.x], 1);
            atomicAdd(&deg[r4.y], 1);
            atomicAdd(&deg[r4.z], 1);
            atomicAdd(&deg[r4.w], 1);
            int u0 = ucnt[r4.x], u1 = ucnt[r4.y], u2 = ucnt[r4.z], u3 = ucnt[r4.w];
            if (u0 > 0) { int i = atomicAdd(&lcnt, 1); if (i < 256) buf[i] = make_int2(c4.x, u0); }
            if (u1 > 0) { int i = atomicAdd(&lcnt, 1); if (i < 256) buf[i] = make_int2(c4.y, u1); }
            if (u2 > 0) { int i = atomicAdd(&lcnt, 1); if (i < 256) buf[i] = make_int2(c4.z, u2); }
            if (u3 > 0) { int i = atomicAdd(&lcnt, 1); if (i < 256) buf[i] = make_int2(c4.w, u3); }
        } else {
            for (int e = base; e < e1; ++e) {
                int r = row[e], c = col[e];
                rkC[e] = (unsigned char)atomicAdd(&hc[c >> 9], 1u);
                atomicAdd(&deg[r], 1);
                int u = ucnt[r];
                if (u > 0) { int i = atomicAdd(&lcnt, 1); if (i < 256) buf[i] = make_int2(c, u); }
            }
        }
    }
    __syncthreads();
    for (int i = t; i < NBUK; i += 512)
        cntC[(size_t)blk * NBUK + i] = (unsigned short)hc[i];
    if (t == 0) {
        int c = lcnt; c = c < 256 ? c : 256;
        lbase = atomicAdd(n_sel, c);
    }
    __syncthreads();
    int c = lcnt; c = c < 256 ? c : 256;
    int b = lbase;
    for (int i = t; i < c; i += 512) {
        int o = b + i;
        if (o < SEL_CAP) { sel_col[o] = buf[i].x; sel_w[o] = (float)buf[i].y; }
    }
}

// ---- stage 2: parallel per-bucket prefix over slices (col side only) -----

__global__ __launch_bounds__(512) void bprefix1_kernel(
        const unsigned short* __restrict__ cntC,
        unsigned short* __restrict__ offC, int* __restrict__ tot) {
    int b = blockIdx.x;
    __shared__ int sm[512];
    int t = threadIdx.x;
    int v = (int)cntC[(size_t)t * NBUK + b];
    sm[t] = v;
    __syncthreads();
    for (int o = 1; o < 512; o <<= 1) {
        int x = (t >= o) ? sm[t - o] : 0;
        __syncthreads();
        sm[t] += x;
        __syncthreads();
    }
    offC[(size_t)t * NBUK + b] = (unsigned short)(sm[t] - v);
    if (t == 511) tot[b] = sm[511];
}

__global__ __launch_bounds__(512) void bprefix2_kernel(
        const int* __restrict__ tot, int* __restrict__ baseC) {
    __shared__ int sm[512];
    int t = threadIdx.x;
    int v = (t < NBUK) ? tot[t] : 0;
    sm[t] = v;
    __syncthreads();
    for (int o = 1; o < 512; o <<= 1) {
        int x = (t >= o) ? sm[t - o] : 0;
        __syncthreads();
        sm[t] += x;
        __syncthreads();
    }
    if (t < NBUK) baseC[t] = sm[t] - v;
    if (t == NBUK - 1) baseC[NBUK] = sm[t];     // == NEDGE
}

// ---- stage 3: placement -- LDS-staged slice sort (col only), burst out ---

__global__ __launch_bounds__(512) void place_kernel(
        const int* __restrict__ row, const int* __restrict__ col,
        const unsigned char* __restrict__ rkC,
        const unsigned short* __restrict__ cntC, const unsigned short* __restrict__ offC,
        const int* __restrict__ baseC, unsigned int* __restrict__ midC) {
    __shared__ int lofC[NBUK], posC[NBUK], cCl[NBUK];
    __shared__ int scan_tmp[512];
    __shared__ unsigned int stC[EPS];
    int blk = blockIdx.x, t = threadIdx.x;
    if (t < NBUK) {
        cCl[t] = (int)cntC[(size_t)blk * NBUK + t];
        posC[t] = baseC[t] + (int)offC[(size_t)blk * NBUK + t];
    }
    __syncthreads();
    scan_tmp[t] = (t < NBUK) ? cCl[t] : 0;
    __syncthreads();
    for (int o = 1; o < 512; o <<= 1) {
        int v = (t >= o) ? scan_tmp[t - o] : 0;
        __syncthreads();
        scan_tmp[t] += v;
        __syncthreads();
    }
    if (t < NBUK) lofC[t] = scan_tmp[t] - cCl[t];
    __syncthreads();
    int e0 = blk * EPS;
    int e1 = e0 + EPS; if (e1 > NEDGE) e1 = NEDGE;
    for (int base = e0 + t * 4; base < e1; base += 2048) {
        if (base + 4 <= e1) {
            int4 r4 = *(const int4*)(row + base);
            int4 c4 = *(const int4*)(col + base);
            uchar4 kc = *(const uchar4*)(rkC + base);
            stC[lofC[c4.x >> 9] + (int)kc.x] = ((unsigned int)(c4.x & 511) << 18) | (unsigned int)r4.x;
            stC[lofC[c4.y >> 9] + (int)kc.y] = ((unsigned int)(c4.y & 511) << 18) | (unsigned int)r4.y;
            stC[lofC[c4.z >> 9] + (int)kc.z] = ((unsigned int)(c4.z & 511) << 18) | (unsigned int)r4.z;
            stC[lofC[c4.w >> 9] + (int)kc.w] = ((unsigned int)(c4.w & 511) << 18) | (unsigned int)r4.w;
        } else {
            for (int e = base; e < e1; ++e) {
                int r = row[e], c = col[e];
                stC[lofC[c >> 9] + (int)rkC[e]] = ((unsigned int)(c & 511) << 18) | (unsigned int)r;
            }
        }
    }
    __syncthreads();
    int wave = t >> 6, lane = t & 63;
    for (int b = wave; b < NBUK; b += 8) {
        int n = cCl[b], lo = lofC[b], dst = posC[b];
        for (int i = lane; i < n; i += 64) midC[dst + i] = stC[lo + i];
    }
}

// ---- stage 4 (fused): col CSR + deg->dinv/dinv2 + embed->bf16 y0 ---------

__global__ __launch_bounds__(1024) void bfinal_kernel(
        const unsigned int* __restrict__ midC, const int* __restrict__ baseC,
        const int* __restrict__ deg,
        const float4* __restrict__ embed,
        int* __restrict__ rptr, int* __restrict__ src_sorted,
        float* __restrict__ dinv, float* __restrict__ dinv2,
        uint2* __restrict__ y0) {
    __shared__ int cnt[512], sm[512], cur[512];
    __shared__ float dinvL[512];
    int b = blockIdx.x, t = threadIdx.x;
    // --- col part ---
    int s0 = baseC[b], s1 = baseC[b + 1];
    if (t < 512) cnt[t] = 0;
    __syncthreads();
    for (int i = s0 + t; i < s1; i += 1024) atomicAdd(&cnt[midC[i] >> 18], 1);
    __syncthreads();
    if (t < 512) sm[t] = cnt[t];
    __syncthreads();
    for (int off = 1; off < 512; off <<= 1) {
        int v = 0;
        if (t < 512 && t >= off) v = sm[t - off];
        __syncthreads();
        if (t < 512) sm[t] += v;
        __syncthreads();
    }
    if (t < 512) {
        int excl = s0 + sm[t] - cnt[t];
        int n = b * 512 + t;
        if (n < NNODES) rptr[n] = excl;
        cur[t] = excl;
    }
    if (b == NBUK - 1 && t == 0) rptr[NNODES] = s1;   // == NEDGE
    if (b == 0 && t < 16) y0[(size_t)NNODES * 16 + t] = make_uint2(0u, 0u); // sentinel zero row
    __syncthreads();
    for (int i = s0 + t; i < s1; i += 1024) {
        unsigned int v = midC[i];
        int dst = atomicAdd(&cur[v >> 18], 1);
        src_sorted[dst] = (int)(v & 0x3FFFFu);
    }
    // --- scale part: read deg (built by bhist global atomics) ---
    if (t < 512) {
        int n = b * 512 + t;
        if (n < NNODES) {
            float d = fmaxf((float)deg[n], 1.0f);
            float di = rsqrtf(d);
            dinv[n] = di; dinv2[n] = 1.0f / d;
            dinvL[t] = di;
        }
    }
    __syncthreads();
    // --- cvt part: y0 = bf16(dinv * embed) for this node range ---
    int nbase = b * 512;
    int nmax = NNODES - nbase; if (nmax > 512) nmax = 512;
    if (nmax < 0) nmax = 0;
    for (int i = t; i < nmax * 16; i += 1024) {
        int ln = i >> 4, slot = i & 15;
        float d = dinvL[ln];
        float4 v = embed[(size_t)(nbase + ln) * 16 + slot];
        unsigned int w0 = (unsigned int)f2bf(v.x * d) | ((unsigned int)f2bf(v.y * d) << 16);
        unsigned int w1 = (unsigned int)f2bf(v.z * d) | ((unsigned int)f2bf(v.w * d) << 16);
        y0[(size_t)(nbase + ln) * 16 + slot] = make_uint2(w0, w1);
    }
}

// ---- propagation: 8 lanes/node, uint4 (8 bf16)/lane; src-prefetch pipeline,
//      parallel sentinel tail (node NNODES is an always-zero row) -----------

#define ACC8(V) do { \
    a0 += __uint_as_float((V).x << 16); a1 += __uint_as_float((V).x & 0xffff0000u); \
    a2 += __uint_as_float((V).y << 16); a3 += __uint_as_float((V).y & 0xffff0000u); \
    a4 += __uint_as_float((V).z << 16); a5 += __uint_as_float((V).z & 0xffff0000u); \
    a6 += __uint_as_float((V).w << 16); a7 += __uint_as_float((V).w & 0xffff0000u); \
} while (0)

__global__ __launch_bounds__(256, 8) void prop_kernel(
        const uint4* __restrict__ x_in, uint4* __restrict__ x_out,
        const int* __restrict__ ptr, const int* __restrict__ src,
        const float* __restrict__ scale) {
    int gid  = blockIdx.x * blockDim.x + threadIdx.x;
    int node = gid >> 3;       // 8 lanes per node
    int sl   = gid & 7;        // lane's 8-dim slot within the row
    if (node > NNODES) return;
    if (node == NNODES) {      // keep sentinel row zero for next layer
        x_out[(size_t)node * 8 + sl] = make_uint4(0u, 0u, 0u, 0u);
        return;
    }
    int i = ptr[node], e = ptr[node + 1];
    float sc = scale[node];
    float a0 = 0.f, a1 = 0.f, a2 = 0.f, a3 = 0.f;
    float a4 = 0.f, a5 = 0.f, a6 = 0.f, a7 = 0.f;
    int p0, p1, p2, p3;
    if (i + 4 <= e) { p0 = src[i]; p1 = src[i + 1]; p2 = src[i + 2]; p3 = src[i + 3]; }
    while (i + 8 <= e) {
        // gathers issue immediately (addresses ready from previous prefetch)
        uint4 w0 = x_in[p0 * 8 + sl];
        uint4 w1 = x_in[p1 * 8 + sl];
        uint4 w2 = x_in[p2 * 8 + sl];
        uint4 w3 = x_in[p3 * 8 + sl];
        p0 = src[i + 4]; p1 = src[i + 5]; p2 = src[i + 6]; p3 = src[i + 7];
        i += 4;
        ACC8(w0); ACC8(w1); ACC8(w2); ACC8(w3);
    }
    if (i + 4 <= e) {
        uint4 w0 = x_in[p0 * 8 + sl];
        uint4 w1 = x_in[p1 * 8 + sl];
        uint4 w2 = x_in[p2 * 8 + sl];
        uint4 w3 = x_in[p3 * 8 + sl];
        i += 4;
        ACC8(w0); ACC8(w1); ACC8(w2); ACC8(w3);
    }
    if (i < e) {               // tail 1..3: clamp to sentinel zero row, gather in parallel
        int q0 = src[i];
        int q1 = (i + 1 < e) ? src[i + 1] : NNODES;
        int q2 = (i + 2 < e) ? src[i + 2] : NNODES;
        uint4 w0 = x_in[q0 * 8 + sl];
        uint4 w1 = x_in[q1 * 8 + sl];
        uint4 w2 = x_in[q2 * 8 + sl];
        ACC8(w0); ACC8(w1); ACC8(w2);
    }
    uint4 o;
    o.x = (unsigned int)f2bf(a0 * sc) | ((unsigned int)f2bf(a1 * sc) << 16);
    o.y = (unsigned int)f2bf(a2 * sc) | ((unsigned int)f2bf(a3 * sc) << 16);
    o.z = (unsigned int)f2bf(a4 * sc) | ((unsigned int)f2bf(a5 * sc) << 16);
    o.w = (unsigned int)f2bf(a6 * sc) | ((unsigned int)f2bf(a7 * sc) << 16);
    x_out[(size_t)node * 8 + sl] = o;
}

// ---- batch / softmax part (x is bf16) -----------------------------------

__global__ void ucnt_kernel(const int* __restrict__ users, int* __restrict__ ucnt) {
    int b = blockIdx.x * blockDim.x + threadIdx.x;
    if (b < BATCH) atomicAdd(&ucnt[users[b]], 1);
}

__global__ __launch_bounds__(256) void ctx_part_kernel(
        const unsigned short* __restrict__ x, const int* __restrict__ users,
        float* __restrict__ partial) {
    __shared__ float sm[256];
    int lane = threadIdx.x & 63, wl = threadIdx.x >> 6;
    int b = blockIdx.x * 4 + wl;
    float v = (b < BATCH) ? bf2f(x[users[b] * DIM + lane]) : 0.0f;
    sm[threadIdx.x] = v;
    __syncthreads();
    if (wl == 0)
        partial[blockIdx.x * 64 + lane] =
            sm[lane] + sm[64 + lane] + sm[128 + lane] + sm[192 + lane];
}

__global__ __launch_bounds__(256) void ctx_reduce_kernel(
        const float* __restrict__ partial, float* __restrict__ ctx) {
    __shared__ float sm[256];
    int lane = threadIdx.x & 63, wl = threadIdx.x >> 6;
    float acc = 0.0f;
    for (int i = wl; i < 256; i += 4) acc += partial[i * 64 + lane];
    sm[threadIdx.x] = acc;
    __syncthreads();
    if (wl == 0)
        ctx[lane] = (sm[lane] + sm[64 + lane] + sm[128 + lane] + sm[192 + lane])
                    * (1.0f / BATCH);
}

__global__ void softmax_kernel(const unsigned short* __restrict__ x,
                               const float* __restrict__ ctx,
                               const int* __restrict__ sel_col,
                               const float* __restrict__ sel_w,
                               const int* __restrict__ n_sel_p,
                               float* __restrict__ S, float* __restrict__ zp) {
    __shared__ float smS[4 * 64];
    __shared__ float smZ[4];
    int lane = threadIdx.x & 63, wl = threadIdx.x >> 6;
    int n = *n_sel_p; if (n > SEL_CAP) n = SEL_CAP;
    float c = ctx[lane];
    float accS = 0.0f, accZ = 0.0f;
    int stride = gridDim.x * 4;
    for (int idx = blockIdx.x * 4 + wl; idx < n; idx += stride) {
        int node = sel_col[idx];
        float xv = bf2f(x[node * DIM + lane]);
        float v = wave_sum64(xv * c);
        float w = sel_w[idx] * __expf(v);
        accS = fmaf(w, xv, accS);
        accZ += w;
    }
    smS[wl * 64 + lane] = accS;
    if (lane == 0) smZ[wl] = accZ;
    __syncthreads();
    if (wl == 0) {
        float s = smS[lane] + smS[64 + lane] + smS[128 + lane] + smS[192 + lane];
        atomicAdd(&S[lane], s);
    }
    if (threadIdx.x == 0) atomicAdd(zp, smZ[0] + smZ[1] + smZ[2] + smZ[3]);
}

__global__ void score_kernel(const unsigned short* __restrict__ x, const int* __restrict__ users,
                             const int* __restrict__ items, const float* __restrict__ S,
                             const float* __restrict__ zp, float* __restrict__ out) {
    int gid = blockIdx.x * blockDim.x + threadIdx.x;
    int b = gid >> 6, lane = gid & 63;
    if (b >= BATCH) return;
    float z = fmaxf(*zp, 1e-12f);
    float na = S[lane] / z;
    int u = users[b], it = items[b] + NUM_USERS;
    float v = bf2f(x[u * DIM + lane]) * (bf2f(x[it * DIM + lane]) + na);
    v = wave_sum64(v);
    if (lane == 0) out[b] = 1.0f / (1.0f + __expf(-v));
}

// ---- launch -------------------------------------------------------------

extern "C" void kernel_launch(void* const* d_in, const int* in_sizes, int n_in,
                              void* d_out, int out_size, void* d_ws, size_t ws_size,
                              hipStream_t stream) {
    const float* embed = (const float*)d_in[0];
    const int*   edge  = (const int*)d_in[1];
    const int*   row   = edge;
    const int*   col   = edge + NEDGE;
    const int*   users = (const int*)d_in[2];
    const int*   items = (const int*)d_in[3];
    float*       out   = (float*)d_out;
    char*        ws    = (char*)d_ws;

    size_t off = 0;
    auto A = [&](size_t bytes) { size_t o = off; off += (bytes + 255) & ~(size_t)255; return o; };
    size_t o_mid   = A((size_t)NEDGE * 4);                  // midC 8MB
    size_t o_xa    = A((size_t)(NNODES + 1) * DIM * 2);     // +1: sentinel zero row
    size_t o_xb    = A((size_t)(NNODES + 1) * DIM * 2);
    size_t o_src   = A((size_t)NEDGE * 4);                  // 8 MB, alive thru prop
    size_t o_rkC   = A((size_t)SLICES * EPS);               // 2 MB
    size_t o_cntC  = A((size_t)SLICES * NBUK * 2);          // 300 KB
    size_t o_offC  = A((size_t)SLICES * NBUK * 2);
    size_t o_tot   = A((size_t)NBUK * 4);
    size_t o_baseC = A((size_t)(NBUK + 1) * 4);
    size_t o_selc  = A((size_t)SEL_CAP * 4);
    size_t o_selw  = A((size_t)SEL_CAP * 4);
    size_t o_part  = A((size_t)256 * 64 * 4);               // ctx partials
    size_t o_zero  = off;                                   // ---- zeroed block ----
    size_t o_ucnt  = A((size_t)NNODES * 4);
    size_t o_deg   = A((size_t)NNODES * 4);
    size_t o_misc  = A(1024);                               // n_sel@0, z@8, S@256
    size_t zero_bytes = off - o_zero;                       // ---- end zero -------
    size_t o_dinv  = A((size_t)NNODES * 4);
    size_t o_dinv2 = A((size_t)NNODES * 4);
    size_t o_rptr  = A((size_t)(NNODES + 1) * 4);
    size_t o_ctx   = A(256);

    unsigned int*   midC = (unsigned int*)(ws + o_mid);
    unsigned short* xa   = (unsigned short*)(ws + o_xa);
    unsigned short* xb   = (unsigned short*)(ws + o_xb);
    int*   srcS  = (int*)(ws + o_src);
    unsigned char*  rkC  = (unsigned char*)(ws + o_rkC);
    unsigned short* cntC = (unsigned short*)(ws + o_cntC);
    unsigned short* offC = (unsigned short*)(ws + o_offC);
    int*   totC  = (int*)(ws + o_tot);
    int*   baseC = (int*)(ws + o_baseC);
    int*   selc  = (int*)(ws + o_selc);
    float* selw  = (float*)(ws + o_selw);
    float* part  = (float*)(ws + o_part);
    int*   ucnt  = (int*)(ws + o_ucnt);
    int*   deg   = (int*)(ws + o_deg);
    int*   nsel  = (int*)(ws + o_misc);
    float* zp    = (float*)(ws + o_misc + 8);
    float* S     = (float*)(ws + o_misc + 256);
    float* dinv  = (float*)(ws + o_dinv);
    float* dinv2 = (float*)(ws + o_dinv2);
    int*   rptr  = (int*)(ws + o_rptr);
    float* ctx   = (float*)(ws + o_ctx);

    hipMemsetAsync(ws + o_zero, 0, zero_bytes, stream);

    ucnt_kernel<<<(BATCH + 255) / 256, 256, 0, stream>>>(users, ucnt);

    // CSR build: col side slice-sorted; row side reduced to deg[] atomics
    bhist_kernel<<<SLICES, 512, 0, stream>>>(row, col, ucnt, deg, cntC, rkC,
                                             nsel, selc, selw);
    bprefix1_kernel<<<NBUK, 512, 0, stream>>>(cntC, offC, totC);
    bprefix2_kernel<<<1, 512, 0, stream>>>(totC, baseC);
    place_kernel<<<SLICES, 512, 0, stream>>>(row, col, rkC, cntC, offC, baseC, midC);
    bfinal_kernel<<<NBUK, 1024, 0, stream>>>(midC, baseC, deg,
                                             (const float4*)embed, rptr, srcS,
                                             dinv, dinv2, (uint2*)xa);

    // layers: y->y (dinv2), y->y (dinv2), y->x (dinv)
    int prop_blocks = ((NNODES + 1) * 8 + 255) / 256;
    prop_kernel<<<prop_blocks, 256, 0, stream>>>((const uint4*)xa, (uint4*)xb, rptr, srcS, dinv2);
    prop_kernel<<<prop_blocks, 256, 0, stream>>>((const uint4*)xb, (uint4*)xa, rptr, srcS, dinv2);
    prop_kernel<<<prop_blocks, 256, 0, stream>>>((const uint4*)xa, (uint4*)xb, rptr, srcS, dinv);
    // final x lives in xb

    // batch softmax aggregation over selected edges (mx = 0, fused)
    ctx_part_kernel<<<256, 256, 0, stream>>>(xb, users, part);
    ctx_reduce_kernel<<<1, 256, 0, stream>>>(part, ctx);
    softmax_kernel<<<LOGIT_BLOCKS, 256, 0, stream>>>(xb, ctx, selc, selw, nsel, S, zp);

    // final scores
    score_kernel<<<(BATCH * 64 + 255) / 256, 256, 0, stream>>>(xb, users, items, S, zp, out);
}

// Round 3
// 304.858 us; speedup vs baseline: 1.1958x; 1.1958x over previous
//
#include <hip/hip_runtime.h>
#include <float.h>
#include <math.h>

#define NUM_USERS 100000
#define NUM_ITEMS 50000
#define NNODES    150000
#define DIM       64
#define NEDGE     2000000
#define BATCH     1024
#define SEL_CAP   (1 << 18)
#define LOGIT_BLOCKS 512

#define SLICES   512                    // edge slices
#define EPS      3908                   // ceil(NEDGE/SLICES) rounded to x4
#define NBUK     293                    // buckets of 512 nodes (293*512=150016)

__device__ __forceinline__ float wave_sum64(float v) {
    #pragma unroll
    for (int off = 32; off > 0; off >>= 1) v += __shfl_xor(v, off, 64);
    return v;
}

__device__ __forceinline__ float bf2f(unsigned short s) {
    return __uint_as_float(((unsigned int)s) << 16);
}
__device__ __forceinline__ unsigned short f2bf(float f) {   // RNE
    unsigned int u = __float_as_uint(f);
    return (unsigned short)((u + 0x7fffu + ((u >> 16) & 1u)) >> 16);
}

// ---- stage 1: per-slice 293-bucket histograms + u8 ranks + fused selection

__global__ __launch_bounds__(512) void bhist_kernel(
        const int* __restrict__ row, const int* __restrict__ col,
        const int* __restrict__ ucnt,
        unsigned short* __restrict__ cntR, unsigned short* __restrict__ cntC,
        unsigned char* __restrict__ rkR, unsigned char* __restrict__ rkC,
        int* __restrict__ n_sel, int* __restrict__ sel_col, float* __restrict__ sel_w) {
    __shared__ unsigned int hr[NBUK], hc[NBUK];
    __shared__ int lcnt, lbase;
    __shared__ int2 buf[256];
    int blk = blockIdx.x, t = threadIdx.x;
    for (int i = t; i < NBUK; i += 512) { hr[i] = 0; hc[i] = 0; }
    if (t == 0) lcnt = 0;
    __syncthreads();
    int e0 = blk * EPS;
    int e1 = e0 + EPS; if (e1 > NEDGE) e1 = NEDGE;
    for (int base = e0 + t * 4; base < e1; base += 2048) {
        if (base + 4 <= e1) {
            int4 r4 = *(const int4*)(row + base);
            int4 c4 = *(const int4*)(col + base);
            uchar4 a, b;
            a.x = (unsigned char)atomicAdd(&hr[r4.x >> 9], 1u);
            a.y = (unsigned char)atomicAdd(&hr[r4.y >> 9], 1u);
            a.z = (unsigned char)atomicAdd(&hr[r4.z >> 9], 1u);
            a.w = (unsigned char)atomicAdd(&hr[r4.w >> 9], 1u);
            b.x = (unsigned char)atomicAdd(&hc[c4.x >> 9], 1u);
            b.y = (unsigned char)atomicAdd(&hc[c4.y >> 9], 1u);
            b.z = (unsigned char)atomicAdd(&hc[c4.z >> 9], 1u);
            b.w = (unsigned char)atomicAdd(&hc[c4.w >> 9], 1u);
            *(uchar4*)(rkR + base) = a;
            *(uchar4*)(rkC + base) = b;
            int u0 = ucnt[r4.x], u1 = ucnt[r4.y], u2 = ucnt[r4.z], u3 = ucnt[r4.w];
            if (u0 > 0) { int i = atomicAdd(&lcnt, 1); if (i < 256) buf[i] = make_int2(c4.x, u0); }
            if (u1 > 0) { int i = atomicAdd(&lcnt, 1); if (i < 256) buf[i] = make_int2(c4.y, u1); }
            if (u2 > 0) { int i = atomicAdd(&lcnt, 1); if (i < 256) buf[i] = make_int2(c4.z, u2); }
            if (u3 > 0) { int i = atomicAdd(&lcnt, 1); if (i < 256) buf[i] = make_int2(c4.w, u3); }
        } else {
            for (int e = base; e < e1; ++e) {
                int r = row[e], c = col[e];
                rkR[e] = (unsigned char)atomicAdd(&hr[r >> 9], 1u);
                rkC[e] = (unsigned char)atomicAdd(&hc[c >> 9], 1u);
                int u = ucnt[r];
                if (u > 0) { int i = atomicAdd(&lcnt, 1); if (i < 256) buf[i] = make_int2(c, u); }
            }
        }
    }
    __syncthreads();
    for (int i = t; i < NBUK; i += 512) {
        cntR[(size_t)blk * NBUK + i] = (unsigned short)hr[i];
        cntC[(size_t)blk * NBUK + i] = (unsigned short)hc[i];
    }
    if (t == 0) {
        int c = lcnt; c = c < 256 ? c : 256;
        lbase = atomicAdd(n_sel, c);
    }
    __syncthreads();
    int c = lcnt; c = c < 256 ? c : 256;
    int b = lbase;
    for (int i = t; i < c; i += 512) {
        int o = b + i;
        if (o < SEL_CAP) { sel_col[o] = buf[i].x; sel_w[o] = (float)buf[i].y; }
    }
}

// ---- stage 2: parallel per-bucket prefix over slices ---------------------

__global__ __launch_bounds__(512) void bprefix1_kernel(
        const unsigned short* __restrict__ cntR, const unsigned short* __restrict__ cntC,
        unsigned short* __restrict__ offR, unsigned short* __restrict__ offC,
        int* __restrict__ totRC) {
    int side = blockIdx.x / NBUK;
    int b = blockIdx.x - side * NBUK;
    const unsigned short* cnt = side ? cntC : cntR;
    unsigned short* off = side ? offC : offR;
    __shared__ int sm[512];
    int t = threadIdx.x;
    int v = (int)cnt[(size_t)t * NBUK + b];
    sm[t] = v;
    __syncthreads();
    for (int o = 1; o < 512; o <<= 1) {
        int x = (t >= o) ? sm[t - o] : 0;
        __syncthreads();
        sm[t] += x;
        __syncthreads();
    }
    off[(size_t)t * NBUK + b] = (unsigned short)(sm[t] - v);
    if (t == 511) totRC[side * NBUK + b] = sm[511];
}

__global__ __launch_bounds__(512) void bprefix2_kernel(
        const int* __restrict__ totRC, int* __restrict__ baseR, int* __restrict__ baseC) {
    const int* tot = totRC + blockIdx.x * NBUK;
    int* base = blockIdx.x ? baseC : baseR;
    __shared__ int sm[512];
    int t = threadIdx.x;
    int v = (t < NBUK) ? tot[t] : 0;
    sm[t] = v;
    __syncthreads();
    for (int o = 1; o < 512; o <<= 1) {
        int x = (t >= o) ? sm[t - o] : 0;
        __syncthreads();
        sm[t] += x;
        __syncthreads();
    }
    if (t < NBUK) base[t] = sm[t] - v;
    if (t == NBUK - 1) base[NBUK] = sm[t];     // == NEDGE
}

// ---- stage 3: placement -- pure LDS-staged slice sort, burst write-out ---

__global__ __launch_bounds__(512) void place_kernel(
        const int* __restrict__ row, const int* __restrict__ col,
        const unsigned char* __restrict__ rkR, const unsigned char* __restrict__ rkC,
        const unsigned short* __restrict__ cntR, const unsigned short* __restrict__ cntC,
        const unsigned short* __restrict__ offR, const unsigned short* __restrict__ offC,
        const int* __restrict__ baseR, const int* __restrict__ baseC,
        unsigned short* __restrict__ midR, unsigned int* __restrict__ midC) {
    __shared__ int lofC[NBUK], lofR[NBUK], posC[NBUK], posR[NBUK];
    __shared__ int cCl[NBUK], cRl[NBUK];
    __shared__ int scan_tmp[512];
    __shared__ unsigned int   stC[EPS];
    __shared__ unsigned short stR[EPS];
    int blk = blockIdx.x, t = threadIdx.x;
    if (t < NBUK) {
        cCl[t] = (int)cntC[(size_t)blk * NBUK + t];
        cRl[t] = (int)cntR[(size_t)blk * NBUK + t];
        posC[t] = baseC[t] + (int)offC[(size_t)blk * NBUK + t];
        posR[t] = baseR[t] + (int)offR[(size_t)blk * NBUK + t];
    }
    __syncthreads();
    scan_tmp[t] = (t < NBUK) ? cCl[t] : 0;
    __syncthreads();
    for (int o = 1; o < 512; o <<= 1) {
        int v = (t >= o) ? scan_tmp[t - o] : 0;
        __syncthreads();
        scan_tmp[t] += v;
        __syncthreads();
    }
    if (t < NBUK) lofC[t] = scan_tmp[t] - cCl[t];
    __syncthreads();
    scan_tmp[t] = (t < NBUK) ? cRl[t] : 0;
    __syncthreads();
    for (int o = 1; o < 512; o <<= 1) {
        int v = (t >= o) ? scan_tmp[t - o] : 0;
        __syncthreads();
        scan_tmp[t] += v;
        __syncthreads();
    }
    if (t < NBUK) lofR[t] = scan_tmp[t] - cRl[t];
    __syncthreads();
    int e0 = blk * EPS;
    int e1 = e0 + EPS; if (e1 > NEDGE) e1 = NEDGE;
    for (int base = e0 + t * 4; base < e1; base += 2048) {
        if (base + 4 <= e1) {
            int4 r4 = *(const int4*)(row + base);
            int4 c4 = *(const int4*)(col + base);
            uchar4 kr = *(const uchar4*)(rkR + base);
            uchar4 kc = *(const uchar4*)(rkC + base);
            stC[lofC[c4.x >> 9] + (int)kc.x] = ((unsigned int)(c4.x & 511) << 18) | (unsigned int)r4.x;
            stC[lofC[c4.y >> 9] + (int)kc.y] = ((unsigned int)(c4.y & 511) << 18) | (unsigned int)r4.y;
            stC[lofC[c4.z >> 9] + (int)kc.z] = ((unsigned int)(c4.z & 511) << 18) | (unsigned int)r4.z;
            stC[lofC[c4.w >> 9] + (int)kc.w] = ((unsigned int)(c4.w & 511) << 18) | (unsigned int)r4.w;
            stR[lofR[r4.x >> 9] + (int)kr.x] = (unsigned short)(r4.x & 511);
            stR[lofR[r4.y >> 9] + (int)kr.y] = (unsigned short)(r4.y & 511);
            stR[lofR[r4.z >> 9] + (int)kr.z] = (unsigned short)(r4.z & 511);
            stR[lofR[r4.w >> 9] + (int)kr.w] = (unsigned short)(r4.w & 511);
        } else {
            for (int e = base; e < e1; ++e) {
                int r = row[e], c = col[e];
                stC[lofC[c >> 9] + (int)rkC[e]] = ((unsigned int)(c & 511) << 18) | (unsigned int)r;
                stR[lofR[r >> 9] + (int)rkR[e]] = (unsigned short)(r & 511);
            }
        }
    }
    __syncthreads();
    int wave = t >> 6, lane = t & 63;
    for (int b = wave; b < NBUK; b += 8) {
        int n = cCl[b], lo = lofC[b], dst = posC[b];
        for (int i = lane; i < n; i += 64) midC[dst + i] = stC[lo + i];
        n = cRl[b]; lo = lofR[b]; dst = posR[b];
        for (int i = lane; i < n; i += 64) midR[dst + i] = stR[lo + i];
    }
}

// ---- stage 4 (fused): col CSR + row deg/dinv + embed->bf16 y0 ------------

__global__ __launch_bounds__(1024) void bfinal_kernel(
        const unsigned int* __restrict__ midC, const int* __restrict__ baseC,
        const unsigned short* __restrict__ midR, const int* __restrict__ baseR,
        const float4* __restrict__ embed,
        int* __restrict__ rptr, int* __restrict__ src_sorted,
        float* __restrict__ dinv, float* __restrict__ dinv2,
        uint2* __restrict__ y0) {
    __shared__ int cnt[512], sm[512], cur[512];
    __shared__ float dinvL[512];
    int b = blockIdx.x, t = threadIdx.x;
    // --- col part ---
    int s0 = baseC[b], s1 = baseC[b + 1];
    if (t < 512) cnt[t] = 0;
    __syncthreads();
    for (int i = s0 + t; i < s1; i += 1024) atomicAdd(&cnt[midC[i] >> 18], 1);
    __syncthreads();
    if (t < 512) sm[t] = cnt[t];
    __syncthreads();
    for (int off = 1; off < 512; off <<= 1) {
        int v = 0;
        if (t < 512 && t >= off) v = sm[t - off];
        __syncthreads();
        if (t < 512) sm[t] += v;
        __syncthreads();
    }
    if (t < 512) {
        int excl = s0 + sm[t] - cnt[t];
        int n = b * 512 + t;
        if (n < NNODES) rptr[n] = excl;
        cur[t] = excl;
    }
    if (b == NBUK - 1 && t == 0) rptr[NNODES] = s1;   // == NEDGE
    if (b == 0 && t < 16) y0[(size_t)NNODES * 16 + t] = make_uint2(0u, 0u); // sentinel zero row
    __syncthreads();
    for (int i = s0 + t; i < s1; i += 1024) {
        unsigned int v = midC[i];
        int dst = atomicAdd(&cur[v >> 18], 1);
        src_sorted[dst] = (int)(v & 0x3FFFFu);
    }
    __syncthreads();
    // --- row part ---
    if (t < 512) cnt[t] = 0;
    __syncthreads();
    int r0 = baseR[b], r1 = baseR[b + 1];
    for (int i = r0 + t; i < r1; i += 1024) atomicAdd(&cnt[midR[i]], 1);
    __syncthreads();
    if (t < 512) {
        int n = b * 512 + t;
        if (n < NNODES) {
            float d = fmaxf((float)cnt[t], 1.0f);
            float di = rsqrtf(d);
            dinv[n] = di; dinv2[n] = 1.0f / d;
            dinvL[t] = di;
        }
    }
    __syncthreads();
    // --- cvt part: y0 = bf16(dinv * embed) for this node range ---
    int nbase = b * 512;
    int nmax = NNODES - nbase; if (nmax > 512) nmax = 512;
    if (nmax < 0) nmax = 0;
    for (int i = t; i < nmax * 16; i += 1024) {
        int ln = i >> 4, slot = i & 15;
        float d = dinvL[ln];
        float4 v = embed[(size_t)(nbase + ln) * 16 + slot];
        unsigned int w0 = (unsigned int)f2bf(v.x * d) | ((unsigned int)f2bf(v.y * d) << 16);
        unsigned int w1 = (unsigned int)f2bf(v.z * d) | ((unsigned int)f2bf(v.w * d) << 16);
        y0[(size_t)(nbase + ln) * 16 + slot] = make_uint2(w0, w1);
    }
}

// ---- propagation: 8 lanes/node, uint4 (8 bf16)/lane; src-prefetch pipeline,
//      parallel sentinel tail (node NNODES is an always-zero row) -----------

#define ACC8(V) do { \
    a0 += __uint_as_float((V).x << 16); a1 += __uint_as_float((V).x & 0xffff0000u); \
    a2 += __uint_as_float((V).y << 16); a3 += __uint_as_float((V).y & 0xffff0000u); \
    a4 += __uint_as_float((V).z << 16); a5 += __uint_as_float((V).z & 0xffff0000u); \
    a6 += __uint_as_float((V).w << 16); a7 += __uint_as_float((V).w & 0xffff0000u); \
} while (0)

__global__ __launch_bounds__(256, 8) void prop_kernel(
        const uint4* __restrict__ x_in, uint4* __restrict__ x_out,
        const int* __restrict__ ptr, const int* __restrict__ src,
        const float* __restrict__ scale) {
    int gid  = blockIdx.x * blockDim.x + threadIdx.x;
    int node = gid >> 3;       // 8 lanes per node
    int sl   = gid & 7;        // lane's 8-dim slot within the row
    if (node > NNODES) return;
    if (node == NNODES) {      // keep sentinel row zero for next layer
        x_out[(size_t)node * 8 + sl] = make_uint4(0u, 0u, 0u, 0u);
        return;
    }
    int i = ptr[node], e = ptr[node + 1];
    float sc = scale[node];
    float a0 = 0.f, a1 = 0.f, a2 = 0.f, a3 = 0.f;
    float a4 = 0.f, a5 = 0.f, a6 = 0.f, a7 = 0.f;
    int p0, p1, p2, p3;
    if (i + 4 <= e) { p0 = src[i]; p1 = src[i + 1]; p2 = src[i + 2]; p3 = src[i + 3]; }
    while (i + 8 <= e) {
        // gathers issue immediately (addresses ready from previous prefetch)
        uint4 w0 = x_in[p0 * 8 + sl];
        uint4 w1 = x_in[p1 * 8 + sl];
        uint4 w2 = x_in[p2 * 8 + sl];
        uint4 w3 = x_in[p3 * 8 + sl];
        p0 = src[i + 4]; p1 = src[i + 5]; p2 = src[i + 6]; p3 = src[i + 7];
        i += 4;
        ACC8(w0); ACC8(w1); ACC8(w2); ACC8(w3);
    }
    if (i + 4 <= e) {
        uint4 w0 = x_in[p0 * 8 + sl];
        uint4 w1 = x_in[p1 * 8 + sl];
        uint4 w2 = x_in[p2 * 8 + sl];
        uint4 w3 = x_in[p3 * 8 + sl];
        i += 4;
        ACC8(w0); ACC8(w1); ACC8(w2); ACC8(w3);
    }
    if (i < e) {               // tail 1..3: clamp to sentinel zero row, gather in parallel
        int q0 = src[i];
        int q1 = (i + 1 < e) ? src[i + 1] : NNODES;
        int q2 = (i + 2 < e) ? src[i + 2] : NNODES;
        uint4 w0 = x_in[q0 * 8 + sl];
        uint4 w1 = x_in[q1 * 8 + sl];
        uint4 w2 = x_in[q2 * 8 + sl];
        ACC8(w0); ACC8(w1); ACC8(w2);
    }
    uint4 o;
    o.x = (unsigned int)f2bf(a0 * sc) | ((unsigned int)f2bf(a1 * sc) << 16);
    o.y = (unsigned int)f2bf(a2 * sc) | ((unsigned int)f2bf(a3 * sc) << 16);
    o.z = (unsigned int)f2bf(a4 * sc) | ((unsigned int)f2bf(a5 * sc) << 16);
    o.w = (unsigned int)f2bf(a6 * sc) | ((unsigned int)f2bf(a7 * sc) << 16);
    x_out[(size_t)node * 8 + sl] = o;
}

// ---- batch / softmax part (x is bf16) -----------------------------------

__global__ void ucnt_kernel(const int* __restrict__ users, int* __restrict__ ucnt) {
    int b = blockIdx.x * blockDim.x + threadIdx.x;
    if (b < BATCH) atomicAdd(&ucnt[users[b]], 1);
}

__global__ __launch_bounds__(256) void ctx_part_kernel(
        const unsigned short* __restrict__ x, const int* __restrict__ users,
        float* __restrict__ partial) {
    __shared__ float sm[256];
    int lane = threadIdx.x & 63, wl = threadIdx.x >> 6;
    int b = blockIdx.x * 4 + wl;
    float v = (b < BATCH) ? bf2f(x[users[b] * DIM + lane]) : 0.0f;
    sm[threadIdx.x] = v;
    __syncthreads();
    if (wl == 0)
        partial[blockIdx.x * 64 + lane] =
            sm[lane] + sm[64 + lane] + sm[128 + lane] + sm[192 + lane];
}

__global__ __launch_bounds__(256) void ctx_reduce_kernel(
        const float* __restrict__ partial, float* __restrict__ ctx) {
    __shared__ float sm[256];
    int lane = threadIdx.x & 63, wl = threadIdx.x >> 6;
    float acc = 0.0f;
    for (int i = wl; i < 256; i += 4) acc += partial[i * 64 + lane];
    sm[threadIdx.x] = acc;
    __syncthreads();
    if (wl == 0)
        ctx[lane] = (sm[lane] + sm[64 + lane] + sm[128 + lane] + sm[192 + lane])
                    * (1.0f / BATCH);
}

__global__ void softmax_kernel(const unsigned short* __restrict__ x,
                               const float* __restrict__ ctx,
                               const int* __restrict__ sel_col,
                               const float* __restrict__ sel_w,
                               const int* __restrict__ n_sel_p,
                               float* __restrict__ S, float* __restrict__ zp) {
    __shared__ float smS[4 * 64];
    __shared__ float smZ[4];
    int lane = threadIdx.x & 63, wl = threadIdx.x >> 6;
    int n = *n_sel_p; if (n > SEL_CAP) n = SEL_CAP;
    float c = ctx[lane];
    float accS = 0.0f, accZ = 0.0f;
    int stride = gridDim.x * 4;
    for (int idx = blockIdx.x * 4 + wl; idx < n; idx += stride) {
        int node = sel_col[idx];
        float xv = bf2f(x[node * DIM + lane]);
        float v = wave_sum64(xv * c);
        float w = sel_w[idx] * __expf(v);
        accS = fmaf(w, xv, accS);
        accZ += w;
    }
    smS[wl * 64 + lane] = accS;
    if (lane == 0) smZ[wl] = accZ;
    __syncthreads();
    if (wl == 0) {
        float s = smS[lane] + smS[64 + lane] + smS[128 + lane] + smS[192 + lane];
        atomicAdd(&S[lane], s);
    }
    if (threadIdx.x == 0) atomicAdd(zp, smZ[0] + smZ[1] + smZ[2] + smZ[3]);
}

__global__ void score_kernel(const unsigned short* __restrict__ x, const int* __restrict__ users,
                             const int* __restrict__ items, const float* __restrict__ S,
                             const float* __restrict__ zp, float* __restrict__ out) {
    int gid = blockIdx.x * blockDim.x + threadIdx.x;
    int b = gid >> 6, lane = gid & 63;
    if (b >= BATCH) return;
    float z = fmaxf(*zp, 1e-12f);
    float na = S[lane] / z;
    int u = users[b], it = items[b] + NUM_USERS;
    float v = bf2f(x[u * DIM + lane]) * (bf2f(x[it * DIM + lane]) + na);
    v = wave_sum64(v);
    if (lane == 0) out[b] = 1.0f / (1.0f + __expf(-v));
}

// ---- launch -------------------------------------------------------------

extern "C" void kernel_launch(void* const* d_in, const int* in_sizes, int n_in,
                              void* d_out, int out_size, void* d_ws, size_t ws_size,
                              hipStream_t stream) {
    const float* embed = (const float*)d_in[0];
    const int*   edge  = (const int*)d_in[1];
    const int*   row   = edge;
    const int*   col   = edge + NEDGE;
    const int*   users = (const int*)d_in[2];
    const int*   items = (const int*)d_in[3];
    float*       out   = (float*)d_out;
    char*        ws    = (char*)d_ws;

    size_t off = 0;
    auto A = [&](size_t bytes) { size_t o = off; off += (bytes + 255) & ~(size_t)255; return o; };
    size_t o_mid   = A((size_t)NEDGE * 4 + (size_t)NEDGE * 2);  // midC 8MB + midR 4MB
    size_t o_xa    = A((size_t)(NNODES + 1) * DIM * 2);     // +1: sentinel zero row
    size_t o_xb    = A((size_t)(NNODES + 1) * DIM * 2);
    size_t o_src   = A((size_t)NEDGE * 4);             // 8 MB, alive thru prop
    size_t o_rkR   = A((size_t)SLICES * EPS);          // 2 MB
    size_t o_rkC   = A((size_t)SLICES * EPS);          // 2 MB
    size_t o_cntR  = A((size_t)SLICES * NBUK * 2);     // 300 KB
    size_t o_cntC  = A((size_t)SLICES * NBUK * 2);
    size_t o_offR  = A((size_t)SLICES * NBUK * 2);
    size_t o_offC  = A((size_t)SLICES * NBUK * 2);
    size_t o_tot   = A((size_t)2 * NBUK * 4);
    size_t o_baseR = A((size_t)(NBUK + 1) * 4);
    size_t o_baseC = A((size_t)(NBUK + 1) * 4);
    size_t o_selc  = A((size_t)SEL_CAP * 4);
    size_t o_selw  = A((size_t)SEL_CAP * 4);
    size_t o_part  = A((size_t)256 * 64 * 4);          // ctx partials
    size_t o_zero  = off;                              // ---- zeroed block ----
    size_t o_ucnt  = A((size_t)NNODES * 4);
    size_t o_misc  = A(1024);                          // n_sel@0, z@8, S@256
    size_t zero_bytes = off - o_zero;                  // ---- end zero -------
    size_t o_dinv  = A((size_t)NNODES * 4);
    size_t o_dinv2 = A((size_t)NNODES * 4);
    size_t o_rptr  = A((size_t)(NNODES + 1) * 4);
    size_t o_ctx   = A(256);

    unsigned int*   midC = (unsigned int*)(ws + o_mid);
    unsigned short* midR = (unsigned short*)(ws + o_mid + (size_t)NEDGE * 4);
    unsigned short* xa   = (unsigned short*)(ws + o_xa);
    unsigned short* xb   = (unsigned short*)(ws + o_xb);
    int*   srcS  = (int*)(ws + o_src);
    unsigned char* rkR = (unsigned char*)(ws + o_rkR);
    unsigned char* rkC = (unsigned char*)(ws + o_rkC);
    unsigned short* cntR = (unsigned short*)(ws + o_cntR);
    unsigned short* cntC = (unsigned short*)(ws + o_cntC);
    unsigned short* offR = (unsigned short*)(ws + o_offR);
    unsigned short* offC = (unsigned short*)(ws + o_offC);
    int*   totRC = (int*)(ws + o_tot);
    int*   baseR = (int*)(ws + o_baseR);
    int*   baseC = (int*)(ws + o_baseC);
    int*   selc  = (int*)(ws + o_selc);
    float* selw  = (float*)(ws + o_selw);
    float* part  = (float*)(ws + o_part);
    int*   ucnt  = (int*)(ws + o_ucnt);
    int*   nsel  = (int*)(ws + o_misc);
    float* zp    = (float*)(ws + o_misc + 8);
    float* S     = (float*)(ws + o_misc + 256);
    float* dinv  = (float*)(ws + o_dinv);
    float* dinv2 = (float*)(ws + o_dinv2);
    int*   rptr  = (int*)(ws + o_rptr);
    float* ctx   = (float*)(ws + o_ctx);

    hipMemsetAsync(ws + o_zero, 0, zero_bytes, stream);

    ucnt_kernel<<<(BATCH + 255) / 256, 256, 0, stream>>>(users, ucnt);

    // atomic-free CSR build (selection fused into bhist)
    bhist_kernel<<<SLICES, 512, 0, stream>>>(row, col, ucnt, cntR, cntC, rkR, rkC,
                                             nsel, selc, selw);
    bprefix1_kernel<<<2 * NBUK, 512, 0, stream>>>(cntR, cntC, offR, offC, totRC);
    bprefix2_kernel<<<2, 512, 0, stream>>>(totRC, baseR, baseC);
    place_kernel<<<SLICES, 512, 0, stream>>>(row, col, rkR, rkC, cntR, cntC,
                                             offR, offC, baseR, baseC, midR, midC);
    // fused: col CSR + row deg + embed->y0 conversion
    bfinal_kernel<<<NBUK, 1024, 0, stream>>>(midC, baseC, midR, baseR,
                                             (const float4*)embed, rptr, srcS,
                                             dinv, dinv2, (uint2*)xa);

    // layers: y->y (dinv2), y->y (dinv2), y->x (dinv)
    int prop_blocks = ((NNODES + 1) * 8 + 255) / 256;
    prop_kernel<<<prop_blocks, 256, 0, stream>>>((const uint4*)xa, (uint4*)xb, rptr, srcS, dinv2);
    prop_kernel<<<prop_blocks, 256, 0, stream>>>((const uint4*)xb, (uint4*)xa, rptr, srcS, dinv2);
    prop_kernel<<<prop_blocks, 256, 0, stream>>>((const uint4*)xa, (uint4*)xb, rptr, srcS, dinv);
    // final x lives in xb

    // batch softmax aggregation over selected edges (mx = 0, fused)
    ctx_part_kernel<<<256, 256, 0, stream>>>(xb, users, part);
    ctx_reduce_kernel<<<1, 256, 0, stream>>>(part, ctx);
    softmax_kernel<<<LOGIT_BLOCKS, 256, 0, stream>>>(xb, ctx, selc, selw, nsel, S, zp);

    // final scores
    score_kernel<<<(BATCH * 64 + 255) / 256, 256, 0, stream>>>(xb, users, items, S, zp, out);
}

// Round 4
// 277.382 us; speedup vs baseline: 1.3142x; 1.0991x over previous
//
#include <hip/hip_runtime.h>
#include <float.h>
#include <math.h>

#define NUM_USERS 100000
#define NUM_ITEMS 50000
#define NNODES    150000
#define DIM       64
#define NEDGE     2000000
#define BATCH     1024
#define SEL_CAP   (1 << 18)
#define LOGIT_BLOCKS 512

#define SLICES   512                    // edge slices
#define EPS      3908                   // ceil(NEDGE/SLICES) rounded to x4
#define NBUK     293                    // buckets of 512 nodes (293*512=150016)

__device__ __forceinline__ float wave_sum64(float v) {
    #pragma unroll
    for (int off = 32; off > 0; off >>= 1) v += __shfl_xor(v, off, 64);
    return v;
}

__device__ __forceinline__ float bf2f(unsigned short s) {
    return __uint_as_float(((unsigned int)s) << 16);
}
__device__ __forceinline__ unsigned short f2bf(float f) {   // RNE
    unsigned int u = __float_as_uint(f);
    return (unsigned short)((u + 0x7fffu + ((u >> 16) & 1u)) >> 16);
}

// ---- stage 1: per-slice 293-bucket histograms + u8 ranks + fused selection

__global__ __launch_bounds__(512) void bhist_kernel(
        const int* __restrict__ row, const int* __restrict__ col,
        const int* __restrict__ ucnt,
        unsigned short* __restrict__ cntR, unsigned short* __restrict__ cntC,
        unsigned char* __restrict__ rkR, unsigned char* __restrict__ rkC,
        int* __restrict__ n_sel, int* __restrict__ sel_col, float* __restrict__ sel_w) {
    __shared__ unsigned int hr[NBUK], hc[NBUK];
    __shared__ int lcnt, lbase;
    __shared__ int2 buf[256];
    int blk = blockIdx.x, t = threadIdx.x;
    for (int i = t; i < NBUK; i += 512) { hr[i] = 0; hc[i] = 0; }
    if (t == 0) lcnt = 0;
    __syncthreads();
    int e0 = blk * EPS;
    int e1 = e0 + EPS; if (e1 > NEDGE) e1 = NEDGE;
    for (int base = e0 + t * 4; base < e1; base += 2048) {
        if (base + 4 <= e1) {
            int4 r4 = *(const int4*)(row + base);
            int4 c4 = *(const int4*)(col + base);
            uchar4 a, b;
            a.x = (unsigned char)atomicAdd(&hr[r4.x >> 9], 1u);
            a.y = (unsigned char)atomicAdd(&hr[r4.y >> 9], 1u);
            a.z = (unsigned char)atomicAdd(&hr[r4.z >> 9], 1u);
            a.w = (unsigned char)atomicAdd(&hr[r4.w >> 9], 1u);
            b.x = (unsigned char)atomicAdd(&hc[c4.x >> 9], 1u);
            b.y = (unsigned char)atomicAdd(&hc[c4.y >> 9], 1u);
            b.z = (unsigned char)atomicAdd(&hc[c4.z >> 9], 1u);
            b.w = (unsigned char)atomicAdd(&hc[c4.w >> 9], 1u);
            *(uchar4*)(rkR + base) = a;
            *(uchar4*)(rkC + base) = b;
            int u0 = ucnt[r4.x], u1 = ucnt[r4.y], u2 = ucnt[r4.z], u3 = ucnt[r4.w];
            if (u0 > 0) { int i = atomicAdd(&lcnt, 1); if (i < 256) buf[i] = make_int2(c4.x, u0); }
            if (u1 > 0) { int i = atomicAdd(&lcnt, 1); if (i < 256) buf[i] = make_int2(c4.y, u1); }
            if (u2 > 0) { int i = atomicAdd(&lcnt, 1); if (i < 256) buf[i] = make_int2(c4.z, u2); }
            if (u3 > 0) { int i = atomicAdd(&lcnt, 1); if (i < 256) buf[i] = make_int2(c4.w, u3); }
        } else {
            for (int e = base; e < e1; ++e) {
                int r = row[e], c = col[e];
                rkR[e] = (unsigned char)atomicAdd(&hr[r >> 9], 1u);
                rkC[e] = (unsigned char)atomicAdd(&hc[c >> 9], 1u);
                int u = ucnt[r];
                if (u > 0) { int i = atomicAdd(&lcnt, 1); if (i < 256) buf[i] = make_int2(c, u); }
            }
        }
    }
    __syncthreads();
    for (int i = t; i < NBUK; i += 512) {
        cntR[(size_t)blk * NBUK + i] = (unsigned short)hr[i];
        cntC[(size_t)blk * NBUK + i] = (unsigned short)hc[i];
    }
    if (t == 0) {
        int c = lcnt; c = c < 256 ? c : 256;
        lbase = atomicAdd(n_sel, c);
    }
    __syncthreads();
    int c = lcnt; c = c < 256 ? c : 256;
    int b = lbase;
    for (int i = t; i < c; i += 512) {
        int o = b + i;
        if (o < SEL_CAP) { sel_col[o] = buf[i].x; sel_w[o] = (float)buf[i].y; }
    }
}

// ---- stage 2: parallel per-bucket prefix over slices ---------------------

__global__ __launch_bounds__(512) void bprefix1_kernel(
        const unsigned short* __restrict__ cntR, const unsigned short* __restrict__ cntC,
        unsigned short* __restrict__ offR, unsigned short* __restrict__ offC,
        int* __restrict__ totRC) {
    int side = blockIdx.x / NBUK;
    int b = blockIdx.x - side * NBUK;
    const unsigned short* cnt = side ? cntC : cntR;
    unsigned short* off = side ? offC : offR;
    __shared__ int sm[512];
    int t = threadIdx.x;
    int v = (int)cnt[(size_t)t * NBUK + b];
    sm[t] = v;
    __syncthreads();
    for (int o = 1; o < 512; o <<= 1) {
        int x = (t >= o) ? sm[t - o] : 0;
        __syncthreads();
        sm[t] += x;
        __syncthreads();
    }
    off[(size_t)t * NBUK + b] = (unsigned short)(sm[t] - v);
    if (t == 511) totRC[side * NBUK + b] = sm[511];
}

__global__ __launch_bounds__(512) void bprefix2_kernel(
        const int* __restrict__ totRC, int* __restrict__ baseR, int* __restrict__ baseC) {
    const int* tot = totRC + blockIdx.x * NBUK;
    int* base = blockIdx.x ? baseC : baseR;
    __shared__ int sm[512];
    int t = threadIdx.x;
    int v = (t < NBUK) ? tot[t] : 0;
    sm[t] = v;
    __syncthreads();
    for (int o = 1; o < 512; o <<= 1) {
        int x = (t >= o) ? sm[t - o] : 0;
        __syncthreads();
        sm[t] += x;
        __syncthreads();
    }
    if (t < NBUK) base[t] = sm[t] - v;
    if (t == NBUK - 1) base[NBUK] = sm[t];     // == NEDGE
}

// ---- stage 3: placement -- pure LDS-staged slice sort, burst write-out ---

__global__ __launch_bounds__(512) void place_kernel(
        const int* __restrict__ row, const int* __restrict__ col,
        const unsigned char* __restrict__ rkR, const unsigned char* __restrict__ rkC,
        const unsigned short* __restrict__ cntR, const unsigned short* __restrict__ cntC,
        const unsigned short* __restrict__ offR, const unsigned short* __restrict__ offC,
        const int* __restrict__ baseR, const int* __restrict__ baseC,
        unsigned short* __restrict__ midR, unsigned int* __restrict__ midC) {
    __shared__ int lofC[NBUK], lofR[NBUK], posC[NBUK], posR[NBUK];
    __shared__ int cCl[NBUK], cRl[NBUK];
    __shared__ int scan_tmp[512];
    __shared__ unsigned int   stC[EPS];
    __shared__ unsigned short stR[EPS];
    int blk = blockIdx.x, t = threadIdx.x;
    if (t < NBUK) {
        cCl[t] = (int)cntC[(size_t)blk * NBUK + t];
        cRl[t] = (int)cntR[(size_t)blk * NBUK + t];
        posC[t] = baseC[t] + (int)offC[(size_t)blk * NBUK + t];
        posR[t] = baseR[t] + (int)offR[(size_t)blk * NBUK + t];
    }
    __syncthreads();
    scan_tmp[t] = (t < NBUK) ? cCl[t] : 0;
    __syncthreads();
    for (int o = 1; o < 512; o <<= 1) {
        int v = (t >= o) ? scan_tmp[t - o] : 0;
        __syncthreads();
        scan_tmp[t] += v;
        __syncthreads();
    }
    if (t < NBUK) lofC[t] = scan_tmp[t] - cCl[t];
    __syncthreads();
    scan_tmp[t] = (t < NBUK) ? cRl[t] : 0;
    __syncthreads();
    for (int o = 1; o < 512; o <<= 1) {
        int v = (t >= o) ? scan_tmp[t - o] : 0;
        __syncthreads();
        scan_tmp[t] += v;
        __syncthreads();
    }
    if (t < NBUK) lofR[t] = scan_tmp[t] - cRl[t];
    __syncthreads();
    int e0 = blk * EPS;
    int e1 = e0 + EPS; if (e1 > NEDGE) e1 = NEDGE;
    for (int base = e0 + t * 4; base < e1; base += 2048) {
        if (base + 4 <= e1) {
            int4 r4 = *(const int4*)(row + base);
            int4 c4 = *(const int4*)(col + base);
            uchar4 kr = *(const uchar4*)(rkR + base);
            uchar4 kc = *(const uchar4*)(rkC + base);
            stC[lofC[c4.x >> 9] + (int)kc.x] = ((unsigned int)(c4.x & 511) << 18) | (unsigned int)r4.x;
            stC[lofC[c4.y >> 9] + (int)kc.y] = ((unsigned int)(c4.y & 511) << 18) | (unsigned int)r4.y;
            stC[lofC[c4.z >> 9] + (int)kc.z] = ((unsigned int)(c4.z & 511) << 18) | (unsigned int)r4.z;
            stC[lofC[c4.w >> 9] + (int)kc.w] = ((unsigned int)(c4.w & 511) << 18) | (unsigned int)r4.w;
            stR[lofR[r4.x >> 9] + (int)kr.x] = (unsigned short)(r4.x & 511);
            stR[lofR[r4.y >> 9] + (int)kr.y] = (unsigned short)(r4.y & 511);
            stR[lofR[r4.z >> 9] + (int)kr.z] = (unsigned short)(r4.z & 511);
            stR[lofR[r4.w >> 9] + (int)kr.w] = (unsigned short)(r4.w & 511);
        } else {
            for (int e = base; e < e1; ++e) {
                int r = row[e], c = col[e];
                stC[lofC[c >> 9] + (int)rkC[e]] = ((unsigned int)(c & 511) << 18) | (unsigned int)r;
                stR[lofR[r >> 9] + (int)rkR[e]] = (unsigned short)(r & 511);
            }
        }
    }
    __syncthreads();
    int wave = t >> 6, lane = t & 63;
    for (int b = wave; b < NBUK; b += 8) {
        int n = cCl[b], lo = lofC[b], dst = posC[b];
        for (int i = lane; i < n; i += 64) midC[dst + i] = stC[lo + i];
        n = cRl[b]; lo = lofR[b]; dst = posR[b];
        for (int i = lane; i < n; i += 64) midR[dst + i] = stR[lo + i];
    }
}

// ---- stage 4 (fused): col CSR + row deg/dinv + embed->bf16 y0 ------------

__global__ __launch_bounds__(1024) void bfinal_kernel(
        const unsigned int* __restrict__ midC, const int* __restrict__ baseC,
        const unsigned short* __restrict__ midR, const int* __restrict__ baseR,
        const float4* __restrict__ embed,
        int* __restrict__ rptr, int* __restrict__ src_sorted,
        float* __restrict__ dinv, float* __restrict__ dinv2,
        uint2* __restrict__ y0) {
    __shared__ int cnt[512], sm[512], cur[512];
    __shared__ float dinvL[512];
    int b = blockIdx.x, t = threadIdx.x;
    // --- col part ---
    int s0 = baseC[b], s1 = baseC[b + 1];
    if (t < 512) cnt[t] = 0;
    __syncthreads();
    for (int i = s0 + t; i < s1; i += 1024) atomicAdd(&cnt[midC[i] >> 18], 1);
    __syncthreads();
    if (t < 512) sm[t] = cnt[t];
    __syncthreads();
    for (int off = 1; off < 512; off <<= 1) {
        int v = 0;
        if (t < 512 && t >= off) v = sm[t - off];
        __syncthreads();
        if (t < 512) sm[t] += v;
        __syncthreads();
    }
    if (t < 512) {
        int excl = s0 + sm[t] - cnt[t];
        int n = b * 512 + t;
        if (n < NNODES) rptr[n] = excl;
        cur[t] = excl;
    }
    if (b == NBUK - 1 && t == 0) rptr[NNODES] = s1;   // == NEDGE
    if (b == 0 && t < 16) y0[(size_t)NNODES * 16 + t] = make_uint2(0u, 0u); // sentinel zero row
    __syncthreads();
    for (int i = s0 + t; i < s1; i += 1024) {
        unsigned int v = midC[i];
        int dst = atomicAdd(&cur[v >> 18], 1);
        src_sorted[dst] = (int)(v & 0x3FFFFu);
    }
    __syncthreads();
    // --- row part ---
    if (t < 512) cnt[t] = 0;
    __syncthreads();
    int r0 = baseR[b], r1 = baseR[b + 1];
    for (int i = r0 + t; i < r1; i += 1024) atomicAdd(&cnt[midR[i]], 1);
    __syncthreads();
    if (t < 512) {
        int n = b * 512 + t;
        if (n < NNODES) {
            float d = fmaxf((float)cnt[t], 1.0f);
            float di = rsqrtf(d);
            dinv[n] = di; dinv2[n] = 1.0f / d;
            dinvL[t] = di;
        }
    }
    __syncthreads();
    // --- cvt part: y0 = bf16(dinv * embed) for this node range ---
    int nbase = b * 512;
    int nmax = NNODES - nbase; if (nmax > 512) nmax = 512;
    if (nmax < 0) nmax = 0;
    for (int i = t; i < nmax * 16; i += 1024) {
        int ln = i >> 4, slot = i & 15;
        float d = dinvL[ln];
        float4 v = embed[(size_t)(nbase + ln) * 16 + slot];
        unsigned int w0 = (unsigned int)f2bf(v.x * d) | ((unsigned int)f2bf(v.y * d) << 16);
        unsigned int w1 = (unsigned int)f2bf(v.z * d) | ((unsigned int)f2bf(v.w * d) << 16);
        y0[(size_t)(nbase + ln) * 16 + slot] = make_uint2(w0, w1);
    }
}

// ---- propagation: 8 lanes/node, uint4 (8 bf16)/lane; src-prefetch pipeline,
//      parallel sentinel tail (node NNODES is an always-zero row) -----------

#define ACC8(V) do { \
    a0 += __uint_as_float((V).x << 16); a1 += __uint_as_float((V).x & 0xffff0000u); \
    a2 += __uint_as_float((V).y << 16); a3 += __uint_as_float((V).y & 0xffff0000u); \
    a4 += __uint_as_float((V).z << 16); a5 += __uint_as_float((V).z & 0xffff0000u); \
    a6 += __uint_as_float((V).w << 16); a7 += __uint_as_float((V).w & 0xffff0000u); \
} while (0)

// shared gather body: accumulate neighbors of `node`, write x_out row
__device__ __forceinline__ void prop_node(
        const uint4* __restrict__ x_in, uint4* __restrict__ x_out,
        const int* __restrict__ ptr, const int* __restrict__ src,
        const float* __restrict__ scale, int node, int sl) {
    int i = ptr[node], e = ptr[node + 1];
    float sc = scale[node];
    float a0 = 0.f, a1 = 0.f, a2 = 0.f, a3 = 0.f;
    float a4 = 0.f, a5 = 0.f, a6 = 0.f, a7 = 0.f;
    int p0, p1, p2, p3;
    if (i + 4 <= e) { p0 = src[i]; p1 = src[i + 1]; p2 = src[i + 2]; p3 = src[i + 3]; }
    while (i + 8 <= e) {
        uint4 w0 = x_in[p0 * 8 + sl];
        uint4 w1 = x_in[p1 * 8 + sl];
        uint4 w2 = x_in[p2 * 8 + sl];
        uint4 w3 = x_in[p3 * 8 + sl];
        p0 = src[i + 4]; p1 = src[i + 5]; p2 = src[i + 6]; p3 = src[i + 7];
        i += 4;
        ACC8(w0); ACC8(w1); ACC8(w2); ACC8(w3);
    }
    if (i + 4 <= e) {
        uint4 w0 = x_in[p0 * 8 + sl];
        uint4 w1 = x_in[p1 * 8 + sl];
        uint4 w2 = x_in[p2 * 8 + sl];
        uint4 w3 = x_in[p3 * 8 + sl];
        i += 4;
        ACC8(w0); ACC8(w1); ACC8(w2); ACC8(w3);
    }
    if (i < e) {               // tail 1..3: clamp to sentinel zero row
        int q0 = src[i];
        int q1 = (i + 1 < e) ? src[i + 1] : NNODES;
        int q2 = (i + 2 < e) ? src[i + 2] : NNODES;
        uint4 w0 = x_in[q0 * 8 + sl];
        uint4 w1 = x_in[q1 * 8 + sl];
        uint4 w2 = x_in[q2 * 8 + sl];
        ACC8(w0); ACC8(w1); ACC8(w2);
    }
    uint4 o;
    o.x = (unsigned int)f2bf(a0 * sc) | ((unsigned int)f2bf(a1 * sc) << 16);
    o.y = (unsigned int)f2bf(a2 * sc) | ((unsigned int)f2bf(a3 * sc) << 16);
    o.z = (unsigned int)f2bf(a4 * sc) | ((unsigned int)f2bf(a5 * sc) << 16);
    o.w = (unsigned int)f2bf(a6 * sc) | ((unsigned int)f2bf(a7 * sc) << 16);
    x_out[(size_t)node * 8 + sl] = o;
}

__global__ __launch_bounds__(256, 8) void prop_kernel(
        const uint4* __restrict__ x_in, uint4* __restrict__ x_out,
        const int* __restrict__ ptr, const int* __restrict__ src,
        const float* __restrict__ scale) {
    int gid  = blockIdx.x * blockDim.x + threadIdx.x;
    int node = gid >> 3;       // 8 lanes per node
    int sl   = gid & 7;        // lane's 8-dim slot within the row
    if (node > NNODES) return;
    if (node == NNODES) {      // keep sentinel row zero for next layer
        x_out[(size_t)node * 8 + sl] = make_uint4(0u, 0u, 0u, 0u);
        return;
    }
    prop_node(x_in, x_out, ptr, src, scale, node, sl);
}

// layer 3: only nodes consumed downstream — users, items+NUM_USERS, sel_col.
// Duplicates recompute bit-identical rows (same CSR order) -> benign.
__global__ __launch_bounds__(256, 8) void prop_list_kernel(
        const uint4* __restrict__ x_in, uint4* __restrict__ x_out,
        const int* __restrict__ ptr, const int* __restrict__ src,
        const float* __restrict__ scale,
        const int* __restrict__ users, const int* __restrict__ items,
        const int* __restrict__ sel_col, const int* __restrict__ n_sel_p) {
    int gid = blockIdx.x * blockDim.x + threadIdx.x;
    int li  = gid >> 3;        // list index
    int sl  = gid & 7;
    int node;
    if (li < BATCH) {
        node = users[li];
    } else if (li < 2 * BATCH) {
        node = items[li - BATCH] + NUM_USERS;
    } else {
        int j = li - 2 * BATCH;
        int n = *n_sel_p; if (n > SEL_CAP) n = SEL_CAP;
        if (j >= n) return;
        node = sel_col[j];
    }
    prop_node(x_in, x_out, ptr, src, scale, node, sl);
}

// ---- batch / softmax part (x is bf16) -----------------------------------

__global__ void ucnt_kernel(const int* __restrict__ users, int* __restrict__ ucnt) {
    int b = blockIdx.x * blockDim.x + threadIdx.x;
    if (b < BATCH) atomicAdd(&ucnt[users[b]], 1);
}

__global__ __launch_bounds__(256) void ctx_part_kernel(
        const unsigned short* __restrict__ x, const int* __restrict__ users,
        float* __restrict__ partial) {
    __shared__ float sm[256];
    int lane = threadIdx.x & 63, wl = threadIdx.x >> 6;
    int b = blockIdx.x * 4 + wl;
    float v = (b < BATCH) ? bf2f(x[users[b] * DIM + lane]) : 0.0f;
    sm[threadIdx.x] = v;
    __syncthreads();
    if (wl == 0)
        partial[blockIdx.x * 64 + lane] =
            sm[lane] + sm[64 + lane] + sm[128 + lane] + sm[192 + lane];
}

__global__ __launch_bounds__(256) void ctx_reduce_kernel(
        const float* __restrict__ partial, float* __restrict__ ctx) {
    __shared__ float sm[256];
    int lane = threadIdx.x & 63, wl = threadIdx.x >> 6;
    float acc = 0.0f;
    for (int i = wl; i < 256; i += 4) acc += partial[i * 64 + lane];
    sm[threadIdx.x] = acc;
    __syncthreads();
    if (wl == 0)
        ctx[lane] = (sm[lane] + sm[64 + lane] + sm[128 + lane] + sm[192 + lane])
                    * (1.0f / BATCH);
}

__global__ void softmax_kernel(const unsigned short* __restrict__ x,
                               const float* __restrict__ ctx,
                               const int* __restrict__ sel_col,
                               const float* __restrict__ sel_w,
                               const int* __restrict__ n_sel_p,
                               float* __restrict__ S, float* __restrict__ zp) {
    __shared__ float smS[4 * 64];
    __shared__ float smZ[4];
    int lane = threadIdx.x & 63, wl = threadIdx.x >> 6;
    int n = *n_sel_p; if (n > SEL_CAP) n = SEL_CAP;
    float c = ctx[lane];
    float accS = 0.0f, accZ = 0.0f;
    int stride = gridDim.x * 4;
    for (int idx = blockIdx.x * 4 + wl; idx < n; idx += stride) {
        int node = sel_col[idx];
        float xv = bf2f(x[node * DIM + lane]);
        float v = wave_sum64(xv * c);
        float w = sel_w[idx] * __expf(v);
        accS = fmaf(w, xv, accS);
        accZ += w;
    }
    smS[wl * 64 + lane] = accS;
    if (lane == 0) smZ[wl] = accZ;
    __syncthreads();
    if (wl == 0) {
        float s = smS[lane] + smS[64 + lane] + smS[128 + lane] + smS[192 + lane];
        atomicAdd(&S[lane], s);
    }
    if (threadIdx.x == 0) atomicAdd(zp, smZ[0] + smZ[1] + smZ[2] + smZ[3]);
}

__global__ void score_kernel(const unsigned short* __restrict__ x, const int* __restrict__ users,
                             const int* __restrict__ items, const float* __restrict__ S,
                             const float* __restrict__ zp, float* __restrict__ out) {
    int gid = blockIdx.x * blockDim.x + threadIdx.x;
    int b = gid >> 6, lane = gid & 63;
    if (b >= BATCH) return;
    float z = fmaxf(*zp, 1e-12f);
    float na = S[lane] / z;
    int u = users[b], it = items[b] + NUM_USERS;
    float v = bf2f(x[u * DIM + lane]) * (bf2f(x[it * DIM + lane]) + na);
    v = wave_sum64(v);
    if (lane == 0) out[b] = 1.0f / (1.0f + __expf(-v));
}

// ---- launch -------------------------------------------------------------

extern "C" void kernel_launch(void* const* d_in, const int* in_sizes, int n_in,
                              void* d_out, int out_size, void* d_ws, size_t ws_size,
                              hipStream_t stream) {
    const float* embed = (const float*)d_in[0];
    const int*   edge  = (const int*)d_in[1];
    const int*   row   = edge;
    const int*   col   = edge + NEDGE;
    const int*   users = (const int*)d_in[2];
    const int*   items = (const int*)d_in[3];
    float*       out   = (float*)d_out;
    char*        ws    = (char*)d_ws;

    size_t off = 0;
    auto A = [&](size_t bytes) { size_t o = off; off += (bytes + 255) & ~(size_t)255; return o; };
    size_t o_mid   = A((size_t)NEDGE * 4 + (size_t)NEDGE * 2);  // midC 8MB + midR 4MB
    size_t o_xa    = A((size_t)(NNODES + 1) * DIM * 2);     // +1: sentinel zero row
    size_t o_xb    = A((size_t)(NNODES + 1) * DIM * 2);
    size_t o_src   = A((size_t)NEDGE * 4);             // 8 MB, alive thru prop
    size_t o_rkR   = A((size_t)SLICES * EPS);          // 2 MB
    size_t o_rkC   = A((size_t)SLICES * EPS);          // 2 MB
    size_t o_cntR  = A((size_t)SLICES * NBUK * 2);     // 300 KB
    size_t o_cntC  = A((size_t)SLICES * NBUK * 2);
    size_t o_offR  = A((size_t)SLICES * NBUK * 2);
    size_t o_offC  = A((size_t)SLICES * NBUK * 2);
    size_t o_tot   = A((size_t)2 * NBUK * 4);
    size_t o_baseR = A((size_t)(NBUK + 1) * 4);
    size_t o_baseC = A((size_t)(NBUK + 1) * 4);
    size_t o_selc  = A((size_t)SEL_CAP * 4);
    size_t o_selw  = A((size_t)SEL_CAP * 4);
    size_t o_part  = A((size_t)256 * 64 * 4);          // ctx partials
    size_t o_zero  = off;                              // ---- zeroed block ----
    size_t o_ucnt  = A((size_t)NNODES * 4);
    size_t o_misc  = A(1024);                          // n_sel@0, z@8, S@256
    size_t zero_bytes = off - o_zero;                  // ---- end zero -------
    size_t o_dinv  = A((size_t)NNODES * 4);
    size_t o_dinv2 = A((size_t)NNODES * 4);
    size_t o_rptr  = A((size_t)(NNODES + 1) * 4);
    size_t o_ctx   = A(256);

    unsigned int*   midC = (unsigned int*)(ws + o_mid);
    unsigned short* midR = (unsigned short*)(ws + o_mid + (size_t)NEDGE * 4);
    unsigned short* xa   = (unsigned short*)(ws + o_xa);
    unsigned short* xb   = (unsigned short*)(ws + o_xb);
    int*   srcS  = (int*)(ws + o_src);
    unsigned char* rkR = (unsigned char*)(ws + o_rkR);
    unsigned char* rkC = (unsigned char*)(ws + o_rkC);
    unsigned short* cntR = (unsigned short*)(ws + o_cntR);
    unsigned short* cntC = (unsigned short*)(ws + o_cntC);
    unsigned short* offR = (unsigned short*)(ws + o_offR);
    unsigned short* offC = (unsigned short*)(ws + o_offC);
    int*   totRC = (int*)(ws + o_tot);
    int*   baseR = (int*)(ws + o_baseR);
    int*   baseC = (int*)(ws + o_baseC);
    int*   selc  = (int*)(ws + o_selc);
    float* selw  = (float*)(ws + o_selw);
    float* part  = (float*)(ws + o_part);
    int*   ucnt  = (int*)(ws + o_ucnt);
    int*   nsel  = (int*)(ws + o_misc);
    float* zp    = (float*)(ws + o_misc + 8);
    float* S     = (float*)(ws + o_misc + 256);
    float* dinv  = (float*)(ws + o_dinv);
    float* dinv2 = (float*)(ws + o_dinv2);
    int*   rptr  = (int*)(ws + o_rptr);
    float* ctx   = (float*)(ws + o_ctx);

    hipMemsetAsync(ws + o_zero, 0, zero_bytes, stream);

    ucnt_kernel<<<(BATCH + 255) / 256, 256, 0, stream>>>(users, ucnt);

    // atomic-free CSR build (selection fused into bhist)
    bhist_kernel<<<SLICES, 512, 0, stream>>>(row, col, ucnt, cntR, cntC, rkR, rkC,
                                             nsel, selc, selw);
    bprefix1_kernel<<<2 * NBUK, 512, 0, stream>>>(cntR, cntC, offR, offC, totRC);
    bprefix2_kernel<<<2, 512, 0, stream>>>(totRC, baseR, baseC);
    place_kernel<<<SLICES, 512, 0, stream>>>(row, col, rkR, rkC, cntR, cntC,
                                             offR, offC, baseR, baseC, midR, midC);
    // fused: col CSR + row deg + embed->y0 conversion
    bfinal_kernel<<<NBUK, 1024, 0, stream>>>(midC, baseC, midR, baseR,
                                             (const float4*)embed, rptr, srcS,
                                             dinv, dinv2, (uint2*)xa);

    // layers 1,2 full: y->y (dinv2), y->y (dinv2); layer 3 selective: y->x (dinv)
    int prop_blocks = ((NNODES + 1) * 8 + 255) / 256;
    prop_kernel<<<prop_blocks, 256, 0, stream>>>((const uint4*)xa, (uint4*)xb, rptr, srcS, dinv2);
    prop_kernel<<<prop_blocks, 256, 0, stream>>>((const uint4*)xb, (uint4*)xa, rptr, srcS, dinv2);
    int list_blocks = ((2 * BATCH + SEL_CAP) * 8 + 255) / 256;
    prop_list_kernel<<<list_blocks, 256, 0, stream>>>((const uint4*)xa, (uint4*)xb,
                                                      rptr, srcS, dinv,
                                                      users, items, selc, nsel);
    // final x rows (users/items/sel) live in xb

    // batch softmax aggregation over selected edges (mx = 0, fused)
    ctx_part_kernel<<<256, 256, 0, stream>>>(xb, users, part);
    ctx_reduce_kernel<<<1, 256, 0, stream>>>(part, ctx);
    softmax_kernel<<<LOGIT_BLOCKS, 256, 0, stream>>>(xb, ctx, selc, selw, nsel, S, zp);

    // final scores
    score_kernel<<<(BATCH * 64 + 255) / 256, 256, 0, stream>>>(xb, users, items, S, zp, out);
}